// Round 9
// baseline (232.281 us; speedup 1.0000x reference)
//
#include <hip/hip_runtime.h>
#include <hip/hip_bf16.h>
#include <math.h>

#define N_TOK 32768
#define C_DIM 256
#define F_DIM 1024
#define E_NUM 16
#define TILE_R 64
#define NCH 32
#define NBLK 1040   // 8 XCD groups x 130; >= max tile count (1024+16)

typedef unsigned short u16;
typedef unsigned int u32;
typedef __attribute__((ext_vector_type(4))) u16 u16x4;
typedef __attribute__((ext_vector_type(8))) u16 u16x8;
typedef __attribute__((ext_vector_type(8))) short bf16x8;
typedef __attribute__((ext_vector_type(4))) u32 u32x4;
typedef __attribute__((ext_vector_type(16))) float f32x16;

#define AS1 __attribute__((address_space(1)))
#define AS3 __attribute__((address_space(3)))

// async global->LDS (prologue only): LDS dest = wave-uniform base + lane*16
__device__ __forceinline__ void gload16(const void* g, void* lds) {
    __builtin_amdgcn_global_load_lds((const AS1 u32*)(uintptr_t)g,
                                     (AS3 u32*)(u32)(uintptr_t)lds, 16, 0, 0);
}

__device__ __forceinline__ u16 f2bf(float f) {
    union { float f; u32 u; } v; v.f = f;
    u32 r = v.u + 0x7fffu + ((v.u >> 16) & 1u);   // RNE
    return (u16)(r >> 16);
}

__device__ __forceinline__ float bf2f(u16 b) {
    union { u32 u; float f; } v; v.u = ((u32)b) << 16;
    return v.f;
}

// ---------------- workspace layout (bytes) ----------------
// 0        topk_idx int[2N]
// 262144   topk_w   f32[2N]
// 524288   tok      int[2N]
// 786432   wgt      f32[2N]
// 1048576  pairpos  int[2N]
// 1310720  counts[16] fill[16] offs[17] tp[17]
// 2097152  xb   bf16[N][C]
// 18874368 w1t  bf16[E][F][C]
// 27262976 w2t  bf16[E][C][F]
// 35651584 ybuf bf16[2N][C]  (MODE 0 only)

// ---- gate: 64 tokens/block, 4 lanes/token, fused x->bf16 conversion ----
__global__ __launch_bounds__(256) void gate_kernel(
    const float* __restrict__ x, const float* __restrict__ gW,
    const float* __restrict__ gb, float* __restrict__ ent_out,
    int* __restrict__ tidx, float* __restrict__ tw, int* __restrict__ counts,
    u16* __restrict__ xb)
{
    __shared__ float gws[E_NUM * C_DIM];
    __shared__ float gbs[E_NUM];
    __shared__ float went[4];
    __shared__ int lc[E_NUM];
    int tid = threadIdx.x;

    for (int i = tid; i < E_NUM * C_DIM / 4; i += 256)
        ((float4*)gws)[i] = ((const float4*)gW)[i];
    if (tid < E_NUM) { gbs[tid] = gb[tid]; lc[tid] = 0; }
    __syncthreads();

    int tok = tid >> 2, q = tid & 3;
    int n = blockIdx.x * 64 + tok;
    const float* xr = x + (size_t)n * C_DIM;

    float4 xv[16];
    #pragma unroll
    for (int j = 0; j < 16; j++)
        xv[j] = *(const float4*)(xr + j * 16 + q * 4);

    #pragma unroll
    for (int j = 0; j < 16; j++) {
        u16x4 o;
        o[0] = f2bf(xv[j].x); o[1] = f2bf(xv[j].y);
        o[2] = f2bf(xv[j].z); o[3] = f2bf(xv[j].w);
        *(u16x4*)(xb + (size_t)n * C_DIM + j * 16 + q * 4) = o;
    }

    float lg[E_NUM];
    #pragma unroll
    for (int e = 0; e < E_NUM; e++) lg[e] = 0.f;
    #pragma unroll
    for (int j = 0; j < 16; j++) {
        #pragma unroll
        for (int e = 0; e < E_NUM; e++) {
            float4 g = *(const float4*)(gws + e * C_DIM + j * 16 + q * 4);
            lg[e] += xv[j].x * g.x + xv[j].y * g.y + xv[j].z * g.z + xv[j].w * g.w;
        }
    }
    #pragma unroll
    for (int e = 0; e < E_NUM; e++) {
        lg[e] += __shfl_xor(lg[e], 1);
        lg[e] += __shfl_xor(lg[e], 2);
        lg[e] += gbs[e];
    }

    float m = lg[0];
    #pragma unroll
    for (int e = 1; e < E_NUM; e++) m = fmaxf(m, lg[e]);
    float s = 0.f, ex[E_NUM];
    #pragma unroll
    for (int e = 0; e < E_NUM; e++) { ex[e] = __expf(lg[e] - m); s += ex[e]; }
    float inv = 1.f / s;
    float ent = 0.f;
    #pragma unroll
    for (int e = 0; e < E_NUM; e++) {
        float p = ex[e] * inv;
        ent -= p * logf(p + 1e-8f);
    }

    float v0 = -1e30f, v1 = -1e30f;
    int i0 = 0, i1 = 0;
    #pragma unroll
    for (int e = 0; e < E_NUM; e++) {
        float l = lg[e];
        if (l > v0) { v1 = v0; i1 = i0; v0 = l; i0 = e; }
        else if (l > v1) { v1 = l; i1 = e; }
    }
    if (q == 0) {
        float w1e = __expf(v1 - v0);
        float z = 1.f + w1e;
        tidx[2 * n] = i0; tidx[2 * n + 1] = i1;
        tw[2 * n] = 1.f / z; tw[2 * n + 1] = w1e / z;
        atomicAdd(&lc[i0], 1);
        atomicAdd(&lc[i1], 1);
    }

    float v = ent;   // 4x duplicated per token -> scale 1/(4N)
    for (int off = 32; off > 0; off >>= 1) v += __shfl_down(v, off);
    int wid = tid >> 6, lane = tid & 63;
    if (lane == 0) went[wid] = v;
    __syncthreads();
    if (tid == 0)
        atomicAdd(ent_out, (went[0] + went[1] + went[2] + went[3]) * (1.0f / (4.0f * N_TOK)));
    if (tid < E_NUM && lc[tid]) atomicAdd(&counts[tid], lc[tid]);
}

__global__ void prefix_kernel(const int* __restrict__ counts,
                              int* __restrict__ offs, int* __restrict__ tp)
{
    if (threadIdx.x == 0 && blockIdx.x == 0) {
        int o = 0, t = 0;
        offs[0] = 0; tp[0] = 0;
        for (int e = 0; e < E_NUM; e++) {
            o += counts[e];
            t += (counts[e] + TILE_R - 1) / TILE_R;
            offs[e + 1] = o;
            tp[e + 1] = t;
        }
    }
}

__global__ __launch_bounds__(256) void scatter_kernel(
    const int* __restrict__ tidx, const float* __restrict__ tw,
    const int* __restrict__ offs, int* __restrict__ fill,
    int* __restrict__ tok, float* __restrict__ wgt, int* __restrict__ pairpos)
{
    __shared__ int lc[E_NUM], lbase[E_NUM];
    int tid = threadIdx.x;
    if (tid < E_NUM) lc[tid] = 0;
    __syncthreads();
    int n = blockIdx.x * 256 + tid;
    int e0 = tidx[2 * n], e1 = tidx[2 * n + 1];
    int r0 = atomicAdd(&lc[e0], 1);
    int r1 = atomicAdd(&lc[e1], 1);
    __syncthreads();
    if (tid < E_NUM) lbase[tid] = offs[tid] + atomicAdd(&fill[tid], lc[tid]);
    __syncthreads();
    int p0 = lbase[e0] + r0, p1 = lbase[e1] + r1;
    tok[p0] = n; wgt[p0] = tw[2 * n];     pairpos[2 * n] = p0;
    tok[p1] = n; wgt[p1] = tw[2 * n + 1]; pairpos[2 * n + 1] = p1;
}

// per-expert transpose+convert: src f32 [R][Cc] -> dst bf16 [Cc][R]
__global__ __launch_bounds__(256) void tcvt_kernel(
    const float* __restrict__ src, u16* __restrict__ dst, int R, int Cc)
{
    __shared__ float t[64][65];
    int e = blockIdx.x;
    int r0 = blockIdx.y << 6, c0 = blockIdx.z << 6;
    const float* s = src + (size_t)e * R * Cc;
    u16* d = dst + (size_t)e * R * Cc;
    int tid = threadIdx.x;
    int rr = tid >> 4, cc = (tid & 15) << 2;
    #pragma unroll
    for (int it = 0; it < 4; it++) {
        float4 v = *(const float4*)(s + (size_t)(r0 + rr + it * 16) * Cc + c0 + cc);
        t[rr + it * 16][cc] = v.x; t[rr + it * 16][cc + 1] = v.y;
        t[rr + it * 16][cc + 2] = v.z; t[rr + it * 16][cc + 3] = v.w;
    }
    __syncthreads();
    int cr = tid >> 3, rq = (tid & 7) << 3;
    #pragma unroll
    for (int it = 0; it < 2; it++) {
        int c = cr + it * 32;
        u16x8 o;
        #pragma unroll
        for (int j = 0; j < 8; j++) o[j] = f2bf(t[rq + j][c]);
        *(u16x8*)(d + (size_t)(c0 + c) * R + r0 + rq) = o;
    }
}

// ---- FFN: 64-token tile, 4 waves (2 blocks/CU), 32x32x16 MFMA ----
// LDS 70144 B: buf0 @0 (w1 16K | w2 16K), buf1 @32768, b1s 4K @65536,
// s_tok @69632, s_w @69888. Chunk = 32 f (NCH=32).
// Wave (wr, wc): phase1 computed redundantly by both wc (full 32-f Ht for
// m-tile wr, lane-local) -> no LDS exchange; phase2 c-split by wc; ONE
// barrier per chunk; sg global loads at prefetch distance 2.
#define B1S_OFF 65536

template <int MODE>
__global__ __launch_bounds__(256, 2) void ffn_mfma(
    const u16* __restrict__ xb, const u16* __restrict__ w1t,
    const u16* __restrict__ w2t, const float* __restrict__ b1,
    const float* __restrict__ b2, const int* __restrict__ tok,
    const float* __restrict__ wgt, const int* __restrict__ offs,
    const int* __restrict__ tp, u16* __restrict__ ybuf,
    float* __restrict__ out)
{
    __shared__ __align__(1024) char smem[70144];
    int* s_tok = (int*)(smem + 69632);
    float* s_w = (float*)(smem + 69888);
    float* b1s = (float*)(smem + B1S_OFF);

    int bidx = blockIdx.x;
    int b = (bidx & 7) * (NBLK / 8) + (bidx >> 3);   // XCD expert-locality remap
    if (b >= tp[E_NUM]) return;
    int e = 0;
    while (b >= tp[e + 1]) e++;
    int base = offs[e] + ((b - tp[e]) << 6);
    int rows = offs[e + 1] - base; if (rows > TILE_R) rows = TILE_R;

    int tid = threadIdx.x;
    int lane = tid & 63, wid = tid >> 6;
    int hi = lane >> 5;
    int wr = wid >> 1, wc = wid & 1;

    const u16* w1e = w1t + (size_t)e * (F_DIM * C_DIM);   // [F][C]
    const u16* w2e = w2t + (size_t)e * (C_DIM * F_DIM);   // [C][F]
    const float* b1e = b1 + e * F_DIM;
    const float* b2e = b2 + e * C_DIM;

    if (tid < TILE_R) {
        int src = (tid < rows) ? base + tid : base;
        s_tok[tid] = tok[src];
        s_w[tid] = (tid < rows) ? wgt[src] : 0.f;
    }
    ((float4*)b1s)[tid] = ((const float4*)b1e)[tid];   // 256 thr x 16B = 4KB
    __syncthreads();

    // ---- prologue: stage x tile (32KB) through buf region, hoist to regs ----
    #pragma unroll
    for (int i = 0; i < 8; i++) {
        int idx = (wid << 3) + i;                       // 0..31 = [mt 2][ks 16]
        int row = ((idx >> 4) << 5) + (lane & 31);
        gload16(xb + ((size_t)s_tok[row] << 8) + ((idx & 15) << 4) + (hi << 3),
                smem + (idx << 10));
    }
    __syncthreads();

    bf16x8 xr[16];     // m-tile wr, 16 k-slices: 64 VGPR
    #pragma unroll
    for (int ks = 0; ks < 16; ks++)
        xr[ks] = *(const bf16x8*)(smem + (wr << 14) + (ks << 10) + (lane << 4));
    __syncthreads();

    // ---- stage chunk 0 -> buf0; load chunk 1 -> sg ----
    u32x4 sg[8];
    #pragma unroll
    for (int i = 0; i < 4; i++) {
        int fid = (wid << 2) + i;
        sg[i] = *(const u32x4*)(w1e + (size_t)(lane & 31) * 256 + (fid << 4) + (hi << 3));
        int swc = fid >> 3, ctl = (fid >> 1) & 3, s2 = fid & 1;
        int c = (swc << 7) + (ctl << 5) + (lane & 31);
        sg[4 + i] = *(const u32x4*)(w2e + (size_t)c * 1024 + (s2 << 4) + (hi << 3));
    }
    #pragma unroll
    for (int i = 0; i < 4; i++) {
        int fid = (wid << 2) + i;
        *(u32x4*)(smem + (fid << 10) + (lane << 4)) = sg[i];
        *(u32x4*)(smem + 16384 + (fid << 10) + (lane << 4)) = sg[4 + i];
    }
    #pragma unroll
    for (int i = 0; i < 4; i++) {
        int fid = (wid << 2) + i;
        sg[i] = *(const u32x4*)(w1e + (size_t)((1 << 5) + (lane & 31)) * 256 + (fid << 4) + (hi << 3));
        int swc = fid >> 3, ctl = (fid >> 1) & 3, s2 = fid & 1;
        int c = (swc << 7) + (ctl << 5) + (lane & 31);
        sg[4 + i] = *(const u32x4*)(w2e + (size_t)c * 1024 + (1 << 5) + (s2 << 4) + (hi << 3));
    }

    f32x16 acc2[4];
    #pragma unroll
    for (int ct = 0; ct < 4; ct++) acc2[ct] = (f32x16)(0.0f);

    for (int ch = 0; ch < NCH; ch++) {
        int cur = ch & 1;
        const char* cbuf = smem + (cur << 15);

        // B0: buf[cur] writes visible; buf[cur^1] free
        asm volatile("s_waitcnt lgkmcnt(0)" ::: "memory");
        __builtin_amdgcn_s_barrier();

        // stage-write sg (chunk ch+1) -> buf[cur^1]; refill sg <- chunk ch+2
        {
            char* nbuf = smem + ((cur ^ 1) << 15);
            #pragma unroll
            for (int i = 0; i < 4; i++) {
                int fid = (wid << 2) + i;
                *(u32x4*)(nbuf + (fid << 10) + (lane << 4)) = sg[i];
                *(u32x4*)(nbuf + 16384 + (fid << 10) + (lane << 4)) = sg[4 + i];
            }
            int chn = ch + 2; if (chn > NCH - 1) chn = NCH - 1;
            #pragma unroll
            for (int i = 0; i < 4; i++) {
                int fid = (wid << 2) + i;
                sg[i] = *(const u32x4*)(w1e + (size_t)((chn << 5) + (lane & 31)) * 256 + (fid << 4) + (hi << 3));
                int swc = fid >> 3, ctl = (fid >> 1) & 3, s2 = fid & 1;
                int c = (swc << 7) + (ctl << 5) + (lane & 31);
                sg[4 + i] = *(const u32x4*)(w2e + (size_t)c * 1024 + (chn << 5) + (s2 << 4) + (hi << 3));
            }
        }

        // ---- phase 1: Ht[32f][32m] = W1ch x X^T, dual chains ----
        const char* w1b = cbuf + (lane << 4);
        f32x16 acc1a = (f32x16)(0.0f), acc1b = (f32x16)(0.0f);
        __builtin_amdgcn_s_setprio(1);
        #pragma unroll
        for (int ks = 0; ks < 8; ks++) {
            bf16x8 a0 = *(const bf16x8*)(w1b + ((2 * ks) << 10));
            bf16x8 a1 = *(const bf16x8*)(w1b + ((2 * ks + 1) << 10));
            acc1a = __builtin_amdgcn_mfma_f32_32x32x16_bf16(a0, xr[2 * ks], acc1a, 0, 0, 0);
            acc1b = __builtin_amdgcn_mfma_f32_32x32x16_bf16(a1, xr[2 * ks + 1], acc1b, 0, 0, 0);
        }
        __builtin_amdgcn_s_setprio(0);

        // bias + relu -> bf16 B-frags (k-slices 0,1 of this 32-f chunk)
        float4 bv0 = *(const float4*)(b1s + (ch << 5) + (hi << 2));
        float4 bv1 = *(const float4*)(b1s + (ch << 5) + (hi << 2) + 8);
        float4 bv2 = *(const float4*)(b1s + (ch << 5) + (hi << 2) + 16);
        float4 bv3 = *(const float4*)(b1s + (ch << 5) + (hi << 2) + 24);
        float bb[16] = {bv0.x, bv0.y, bv0.z, bv0.w, bv1.x, bv1.y, bv1.z, bv1.w,
                        bv2.x, bv2.y, bv2.z, bv2.w, bv3.x, bv3.y, bv3.z, bv3.w};
        float h[16];
        #pragma unroll
        for (int r = 0; r < 16; r++)
            h[r] = fmaxf(acc1a[r] + acc1b[r] + bb[r], 0.f);
        u32 w[8];
        #pragma unroll
        for (int t = 0; t < 8; t++)
            asm("v_cvt_pk_bf16_f32 %0, %1, %2" : "=v"(w[t]) : "v"(h[2 * t]), "v"(h[2 * t + 1]));
        asm volatile("v_permlane32_swap_b32 %0, %1" : "+v"(w[0]), "+v"(w[2]));
        asm volatile("v_permlane32_swap_b32 %0, %1" : "+v"(w[1]), "+v"(w[3]));
        asm volatile("v_permlane32_swap_b32 %0, %1" : "+v"(w[4]), "+v"(w[6]));
        asm volatile("v_permlane32_swap_b32 %0, %1" : "+v"(w[5]), "+v"(w[7]));
        union { u32x4 u; bf16x8 v; } fr0, fr1;
        fr0.u = (u32x4){w[0], w[1], w[2], w[3]};
        fr1.u = (u32x4){w[4], w[5], w[6], w[7]};

        // ---- phase 2: acc2[ctl] += W2frag(wc,ctl,s2) x Ht(s2), s2=0,1 ----
        const char* w2b = cbuf + 16384 + (wc << 13) + (lane << 4);
        __builtin_amdgcn_s_setprio(1);
        #pragma unroll
        for (int ctl = 0; ctl < 4; ctl++) {
            bf16x8 a0 = *(const bf16x8*)(w2b + (ctl << 11));
            bf16x8 a1 = *(const bf16x8*)(w2b + (ctl << 11) + 1024);
            acc2[ctl] = __builtin_amdgcn_mfma_f32_32x32x16_bf16(a0, fr0.v, acc2[ctl], 0, 0, 0);
            acc2[ctl] = __builtin_amdgcn_mfma_f32_32x32x16_bf16(a1, fr1.v, acc2[ctl], 0, 0, 0);
        }
        __builtin_amdgcn_s_setprio(0);
    }

    // ---- epilogue: wave owns (m-tile wr) x (c-half wc), full sums ----
    int m = (wr << 5) + (lane & 31);
    if (m < rows) {
        if (MODE == 0) {
            u16* yr = ybuf + ((size_t)(base + m) << 8) + (wc << 7);
            #pragma unroll
            for (int ctl = 0; ctl < 4; ctl++) {
                #pragma unroll
                for (int rq = 0; rq < 4; rq++) {
                    int c = (ctl << 5) + (rq << 3) + (hi << 2);
                    u16x4 o;
                    o[0] = f2bf(acc2[ctl][4 * rq]);
                    o[1] = f2bf(acc2[ctl][4 * rq + 1]);
                    o[2] = f2bf(acc2[ctl][4 * rq + 2]);
                    o[3] = f2bf(acc2[ctl][4 * rq + 3]);
                    *(u16x4*)(yr + c) = o;
                }
            }
        } else {
            float wgt_m = s_w[m];
            float* orow = out + ((size_t)s_tok[m] << 8) + (wc << 7);
            const float* b2w = b2e + (wc << 7);
            #pragma unroll
            for (int ctl = 0; ctl < 4; ctl++) {
                #pragma unroll
                for (int rq = 0; rq < 4; rq++) {
                    int c = (ctl << 5) + (rq << 3) + (hi << 2);
                    #pragma unroll
                    for (int l = 0; l < 4; l++)
                        atomicAdd(&orow[c + l],
                                  wgt_m * (acc2[ctl][4 * rq + l] + b2w[c + l]));
                }
            }
        }
    }
}

__global__ __launch_bounds__(256) void combine_kernel(
    const u16* __restrict__ ybuf, const int* __restrict__ tidx,
    const float* __restrict__ tw, const int* __restrict__ pairpos,
    const float* __restrict__ b2, float* __restrict__ out)
{
    int idx = blockIdx.x * 256 + threadIdx.x;
    int n = idx >> 6;
    int q = (idx & 63) << 2;
    int e0 = tidx[2 * n], e1 = tidx[2 * n + 1];
    float w0 = tw[2 * n], w1 = tw[2 * n + 1];
    int p0 = pairpos[2 * n], p1 = pairpos[2 * n + 1];
    u16x4 y0 = *(const u16x4*)(ybuf + ((size_t)p0 << 8) + q);
    u16x4 y1 = *(const u16x4*)(ybuf + ((size_t)p1 << 8) + q);
    float4 c0 = *(const float4*)(b2 + (e0 << 8) + q);
    float4 c1 = *(const float4*)(b2 + (e1 << 8) + q);
    float4 o;
    o.x = w0 * (bf2f(y0[0]) + c0.x) + w1 * (bf2f(y1[0]) + c1.x);
    o.y = w0 * (bf2f(y0[1]) + c0.y) + w1 * (bf2f(y1[1]) + c1.y);
    o.z = w0 * (bf2f(y0[2]) + c0.z) + w1 * (bf2f(y1[2]) + c1.z);
    o.w = w0 * (bf2f(y0[3]) + c0.w) + w1 * (bf2f(y1[3]) + c1.w);
    *(float4*)(out + ((size_t)n << 8) + q) = o;
}

extern "C" void kernel_launch(void* const* d_in, const int* in_sizes, int n_in,
                              void* d_out, int out_size, void* d_ws, size_t ws_size,
                              hipStream_t stream)
{
    const float* x   = (const float*)d_in[0];
    const float* gW  = (const float*)d_in[1];
    const float* gb  = (const float*)d_in[2];
    const float* W1  = (const float*)d_in[3];
    const float* b1  = (const float*)d_in[4];
    const float* W2  = (const float*)d_in[5];
    const float* b2  = (const float*)d_in[6];
    float* out = (float*)d_out;

    char* ws = (char*)d_ws;
    int*   topk_idx = (int*)(ws + 0);
    float* topk_w   = (float*)(ws + 262144);
    int*   tok      = (int*)(ws + 524288);
    float* wgt      = (float*)(ws + 786432);
    int*   pairpos  = (int*)(ws + 1048576);
    int*   counts   = (int*)(ws + 1310720);
    int*   fill     = (int*)(ws + 1310784);
    int*   offs     = (int*)(ws + 1310848);
    int*   tp       = (int*)(ws + 1310916);

    const size_t XB_OFF  = 2097152;
    const size_t W1T_OFF = 18874368;
    const size_t W2T_OFF = 27262976;
    const size_t Y_OFF   = 35651584;
    const size_t WS_FULL = Y_OFF + (size_t)2 * N_TOK * C_DIM * 2;  // bf16 ybuf

    u16* xb  = (u16*)(ws + XB_OFF);
    u16* w1t = (u16*)(ws + W1T_OFF);
    u16* w2t = (u16*)(ws + W2T_OFF);
    u16* ybuf = (u16*)(ws + Y_OFF);

    int mode = (ws_size >= WS_FULL) ? 0 : 1;

    float* ent_out = out + (size_t)N_TOK * C_DIM;

    if (mode == 0) {
        hipMemsetAsync(ent_out, 0, sizeof(float), stream);
    } else {
        hipMemsetAsync(d_out, 0, (size_t)(N_TOK * C_DIM + 1) * sizeof(float), stream);
    }
    hipMemsetAsync(counts, 0, 2 * E_NUM * sizeof(int), stream);

    gate_kernel<<<N_TOK / 64, 256, 0, stream>>>(x, gW, gb, ent_out,
                                                topk_idx, topk_w, counts, xb);
    prefix_kernel<<<1, 64, 0, stream>>>(counts, offs, tp);
    scatter_kernel<<<N_TOK / 256, 256, 0, stream>>>(topk_idx, topk_w, offs,
                                                    fill, tok, wgt, pairpos);
    tcvt_kernel<<<dim3(E_NUM, C_DIM / 64, F_DIM / 64), 256, 0, stream>>>(W1, w1t, C_DIM, F_DIM);
    tcvt_kernel<<<dim3(E_NUM, F_DIM / 64, C_DIM / 64), 256, 0, stream>>>(W2, w2t, F_DIM, C_DIM);

    if (mode == 0) {
        ffn_mfma<0><<<NBLK, 256, 0, stream>>>(xb, w1t, w2t, b1, b2, tok, wgt,
                                              offs, tp, ybuf, out);
        combine_kernel<<<N_TOK * 64 / 256, 256, 0, stream>>>(ybuf, topk_idx,
                                                             topk_w, pairpos, b2, out);
    } else {
        ffn_mfma<1><<<NBLK, 256, 0, stream>>>(xb, w1t, w2t, b1, b2, tok, wgt,
                                              offs, tp, ybuf, out);
    }
}

// Round 11
// 183.453 us; speedup vs baseline: 1.2662x; 1.2662x over previous
//
#include <hip/hip_runtime.h>
#include <hip/hip_bf16.h>
#include <math.h>

#define N_TOK 32768
#define C_DIM 256
#define F_DIM 1024
#define E_NUM 16
#define TILE_R 128
#define NCH 16
#define NBLK 544   // 8 XCD groups x 68

typedef unsigned short u16;
typedef unsigned int u32;
typedef __attribute__((ext_vector_type(4))) u16 u16x4;
typedef __attribute__((ext_vector_type(8))) u16 u16x8;
typedef __attribute__((ext_vector_type(8))) short bf16x8;
typedef __attribute__((ext_vector_type(4))) u32 u32x4;
typedef __attribute__((ext_vector_type(16))) float f32x16;

#define AS1 __attribute__((address_space(1)))
#define AS3 __attribute__((address_space(3)))

// async global->LDS: LDS dest = wave-uniform base + lane*16; global src per-lane
__device__ __forceinline__ void gload16(const void* g, void* lds) {
    __builtin_amdgcn_global_load_lds((const AS1 u32*)(uintptr_t)g,
                                     (AS3 u32*)(u32)(uintptr_t)lds, 16, 0, 0);
}

__device__ __forceinline__ u16 f2bf(float f) {
    union { float f; u32 u; } v; v.f = f;
    u32 r = v.u + 0x7fffu + ((v.u >> 16) & 1u);   // RNE
    return (u16)(r >> 16);
}

__device__ __forceinline__ float bf2f(u16 b) {
    union { u32 u; float f; } v; v.u = ((u32)b) << 16;
    return v.f;
}

// ---------------- workspace layout (bytes) ----------------
// 0        topk_idx int[2N]
// 262144   topk_w   f32[2N]
// 524288   tok      int[2N]
// 786432   wgt      f32[2N]
// 1048576  pairpos  int[2N]
// 1310720  counts[16] fill[16] offs[17] tp[17]
// 2097152  xb   bf16[N][C]
// 18874368 w1f  frag-linear bf16 [(e*32+ft)*16+ks][64 lanes][8]  (8.4 MB)
// 27262976 w2f  frag-linear bf16 [(e*8+ct)*64+kf][64 lanes][8]   (8.4 MB)
// 35651584 ybuf bf16[2N][C]

// ---- gate: 64 tokens/block, 4 lanes/token, fused x->bf16 conversion ----
__global__ __launch_bounds__(256) void gate_kernel(
    const float* __restrict__ x, const float* __restrict__ gW,
    const float* __restrict__ gb, float* __restrict__ ent_out,
    int* __restrict__ tidx, float* __restrict__ tw, int* __restrict__ counts,
    u16* __restrict__ xb)
{
    __shared__ float gws[E_NUM * C_DIM];
    __shared__ float gbs[E_NUM];
    __shared__ float went[4];
    __shared__ int lc[E_NUM];
    int tid = threadIdx.x;

    for (int i = tid; i < E_NUM * C_DIM / 4; i += 256)
        ((float4*)gws)[i] = ((const float4*)gW)[i];
    if (tid < E_NUM) { gbs[tid] = gb[tid]; lc[tid] = 0; }
    __syncthreads();

    int tok = tid >> 2, q = tid & 3;
    int n = blockIdx.x * 64 + tok;
    const float* xr = x + (size_t)n * C_DIM;

    float4 xv[16];
    #pragma unroll
    for (int j = 0; j < 16; j++)
        xv[j] = *(const float4*)(xr + j * 16 + q * 4);

    #pragma unroll
    for (int j = 0; j < 16; j++) {
        u16x4 o;
        o[0] = f2bf(xv[j].x); o[1] = f2bf(xv[j].y);
        o[2] = f2bf(xv[j].z); o[3] = f2bf(xv[j].w);
        *(u16x4*)(xb + (size_t)n * C_DIM + j * 16 + q * 4) = o;
    }

    float lg[E_NUM];
    #pragma unroll
    for (int e = 0; e < E_NUM; e++) lg[e] = 0.f;
    #pragma unroll
    for (int j = 0; j < 16; j++) {
        #pragma unroll
        for (int e = 0; e < E_NUM; e++) {
            float4 g = *(const float4*)(gws + e * C_DIM + j * 16 + q * 4);
            lg[e] += xv[j].x * g.x + xv[j].y * g.y + xv[j].z * g.z + xv[j].w * g.w;
        }
    }
    #pragma unroll
    for (int e = 0; e < E_NUM; e++) {
        lg[e] += __shfl_xor(lg[e], 1);
        lg[e] += __shfl_xor(lg[e], 2);
        lg[e] += gbs[e];
    }

    float m = lg[0];
    #pragma unroll
    for (int e = 1; e < E_NUM; e++) m = fmaxf(m, lg[e]);
    float s = 0.f, ex[E_NUM];
    #pragma unroll
    for (int e = 0; e < E_NUM; e++) { ex[e] = __expf(lg[e] - m); s += ex[e]; }
    float inv = 1.f / s;
    float ent = 0.f;
    #pragma unroll
    for (int e = 0; e < E_NUM; e++) {
        float p = ex[e] * inv;
        ent -= p * logf(p + 1e-8f);
    }

    float v0 = -1e30f, v1 = -1e30f;
    int i0 = 0, i1 = 0;
    #pragma unroll
    for (int e = 0; e < E_NUM; e++) {
        float l = lg[e];
        if (l > v0) { v1 = v0; i1 = i0; v0 = l; i0 = e; }
        else if (l > v1) { v1 = l; i1 = e; }
    }
    if (q == 0) {
        float w1e = __expf(v1 - v0);
        float z = 1.f + w1e;
        tidx[2 * n] = i0; tidx[2 * n + 1] = i1;
        tw[2 * n] = 1.f / z; tw[2 * n + 1] = w1e / z;
        atomicAdd(&lc[i0], 1);
        atomicAdd(&lc[i1], 1);
    }

    float v = ent;   // 4x duplicated per token -> scale 1/(4N)
    for (int off = 32; off > 0; off >>= 1) v += __shfl_down(v, off);
    int wid = tid >> 6, lane = tid & 63;
    if (lane == 0) went[wid] = v;
    __syncthreads();
    if (tid == 0)
        atomicAdd(ent_out, (went[0] + went[1] + went[2] + went[3]) * (1.0f / (4.0f * N_TOK)));
    if (tid < E_NUM && lc[tid]) atomicAdd(&counts[tid], lc[tid]);
}

__global__ void prefix_kernel(const int* __restrict__ counts,
                              int* __restrict__ offs, int* __restrict__ tp)
{
    if (threadIdx.x == 0 && blockIdx.x == 0) {
        int o = 0, t = 0;
        offs[0] = 0; tp[0] = 0;
        for (int e = 0; e < E_NUM; e++) {
            o += counts[e];
            t += (counts[e] + TILE_R - 1) / TILE_R;
            offs[e + 1] = o;
            tp[e + 1] = t;
        }
    }
}

__global__ __launch_bounds__(256) void scatter_kernel(
    const int* __restrict__ tidx, const float* __restrict__ tw,
    const int* __restrict__ offs, int* __restrict__ fill,
    int* __restrict__ tok, float* __restrict__ wgt, int* __restrict__ pairpos)
{
    __shared__ int lc[E_NUM], lbase[E_NUM];
    int tid = threadIdx.x;
    if (tid < E_NUM) lc[tid] = 0;
    __syncthreads();
    int n = blockIdx.x * 256 + tid;
    int e0 = tidx[2 * n], e1 = tidx[2 * n + 1];
    int r0 = atomicAdd(&lc[e0], 1);
    int r1 = atomicAdd(&lc[e1], 1);
    __syncthreads();
    if (tid < E_NUM) lbase[tid] = offs[tid] + atomicAdd(&fill[tid], lc[tid]);
    __syncthreads();
    int p0 = lbase[e0] + r0, p1 = lbase[e1] + r1;
    tok[p0] = n; wgt[p0] = tw[2 * n];     pairpos[2 * n] = p0;
    tok[p1] = n; wgt[p1] = tw[2 * n + 1]; pairpos[2 * n + 1] = p1;
}

// ---- frag-izers: emit frag-linear bf16 layouts (1 KB contiguous per frag) ----
// w1f frag (e,ft,ks): lane l, elem j = W1[e][c = ks*16+(l>>5)*8+j][f = ft*32+(l&31)]
__global__ __launch_bounds__(256) void tcvt_w1f(
    const float* __restrict__ W1, u16* __restrict__ w1f)
{
    __shared__ float t[256][33];
    int e = blockIdx.x, ft = blockIdx.y;
    int tid = threadIdx.x;
    const float* src = W1 + ((size_t)e * C_DIM) * F_DIM + (size_t)tid * F_DIM + ft * 32;
    #pragma unroll
    for (int j = 0; j < 8; j++) {
        float4 v = *(const float4*)(src + j * 4);
        t[tid][j * 4] = v.x; t[tid][j * 4 + 1] = v.y;
        t[tid][j * 4 + 2] = v.z; t[tid][j * 4 + 3] = v.w;
    }
    __syncthreads();
    int l = tid & 63, ksq = tid >> 6;
    #pragma unroll
    for (int p = 0; p < 4; p++) {
        int ks = ksq * 4 + p;
        int c0 = ks * 16 + (l >> 5) * 8;
        u16x8 o;
        #pragma unroll
        for (int j = 0; j < 8; j++) o[j] = f2bf(t[c0 + j][l & 31]);
        *(u16x8*)(w1f + ((size_t)((e * 32 + ft) * 16 + ks)) * 512 + l * 8) = o;
    }
}

// w2f frag (e,ct,kf): lane l, elem j = W2[e][f = kf*16+(l>>5)*8+j][c = ct*32+(l&31)]
__global__ __launch_bounds__(256) void tcvt_w2f(
    const float* __restrict__ W2, u16* __restrict__ w2f)
{
    __shared__ float t[256][33];
    int e = blockIdx.x, ct = blockIdx.y, fq = blockIdx.z;
    int tid = threadIdx.x;
    const float* src = W2 + ((size_t)e * F_DIM + fq * 256 + tid) * C_DIM + ct * 32;
    #pragma unroll
    for (int j = 0; j < 8; j++) {
        float4 v = *(const float4*)(src + j * 4);
        t[tid][j * 4] = v.x; t[tid][j * 4 + 1] = v.y;
        t[tid][j * 4 + 2] = v.z; t[tid][j * 4 + 3] = v.w;
    }
    __syncthreads();
    int l = tid & 63, kq = tid >> 6;
    #pragma unroll
    for (int p = 0; p < 4; p++) {
        int kfl = kq * 4 + p;
        int f0 = kfl * 16 + (l >> 5) * 8;
        u16x8 o;
        #pragma unroll
        for (int j = 0; j < 8; j++) o[j] = f2bf(t[f0 + j][l & 31]);
        *(u16x8*)(w2f + ((size_t)((e * 8 + ct) * 64 + fq * 16 + kfl)) * 512 + l * 8) = o;
    }
}

// ---- FFN: 128-token tile, 8 waves, 32x32x16 MFMA, gload_lds 2-phase ----
// LDS 152576: buf0 @0 (w1 32K | w2 32K), buf1 @65536, b1s @131072 (4K),
// hs @135168 (16K), s_tok @151552, s_w @152064.
// Per chunk: stage-all-at-top (gload_lds, frag-linear src) -> p1 -> hs
// exchange (lgkm-only barrier) -> p2 -> explicit vmcnt(0)+lgkm(0)+s_barrier
// (stage aged one full chunk at the drain).
// acc2[4] holds FULL-K sums (hs exchange) -> epilogue: each wave writes its
// own (m-tile wr) x (c-half wc). NO cross-wave reduction (r10 bug: OOB acc2[4..7]).
#define HS_OFF  135168
#define B1S_OFF 131072

// stage chunk CHN into buffer at nbuf (8 gload16 per wave, frag-linear src)
#define STAGE_CHUNK(CHN, NBUF)                                                \
    if (wid < 4) {                                                            \
        _Pragma("unroll")                                                     \
        for (int i = 0; i < 8; i++) {                                         \
            int fid = (wid << 3) + i;                                         \
            gload16(w1fe + (((size_t)((CHN) << 5) + fid) << 9) + (lane << 3), \
                    (NBUF) + (fid << 10));                                    \
        }                                                                     \
    } else {                                                                  \
        _Pragma("unroll")                                                     \
        for (int i = 0; i < 8; i++) {                                         \
            int g = ((wid - 4) << 3) + i;                                     \
            int ct = g >> 2, kfl = g & 3;                                     \
            gload16(w2fe + (((size_t)(ct << 6) + ((CHN) << 2) + kfl) << 9) + (lane << 3), \
                    (NBUF) + 32768 + (g << 10));                              \
        }                                                                     \
    }

template <int MODE>
__global__ __launch_bounds__(512, 2) void ffn_mfma(
    const u16* __restrict__ xb, const u16* __restrict__ w1f,
    const u16* __restrict__ w2f, const float* __restrict__ b1,
    const float* __restrict__ b2, const int* __restrict__ tok,
    const float* __restrict__ wgt, const int* __restrict__ offs,
    const int* __restrict__ tp, u16* __restrict__ ybuf,
    float* __restrict__ out)
{
    __shared__ __align__(1024) char smem[152576];
    int* s_tok = (int*)(smem + 151552);
    float* s_w = (float*)(smem + 152064);
    float* b1s = (float*)(smem + B1S_OFF);

    int bidx = blockIdx.x;
    int b = (bidx & 7) * (NBLK / 8) + (bidx >> 3);   // XCD expert-locality remap
    if (b >= tp[E_NUM]) return;
    int e = 0;
    while (b >= tp[e + 1]) e++;
    int base = offs[e] + ((b - tp[e]) << 7);
    int rows = offs[e + 1] - base; if (rows > TILE_R) rows = TILE_R;

    int tid = threadIdx.x;
    int lane = tid & 63, wid = tid >> 6;
    int hi = lane >> 5;
    int wr = wid >> 1, wc = wid & 1;

    const u16* w1fe = w1f + ((size_t)e << 9) * 512;   // e * 512 frags * 512 u16
    const u16* w2fe = w2f + ((size_t)e << 9) * 512;
    const float* b1e = b1 + e * F_DIM;
    const float* b2e = b2 + e * C_DIM;

    if (tid < TILE_R) {
        int src = (tid < rows) ? base + tid : base;
        s_tok[tid] = tok[src];
        s_w[tid] = (tid < rows) ? wgt[src] : 0.f;
    }
    if (tid < 256) ((float4*)b1s)[tid] = ((const float4*)b1e)[tid];
    __syncthreads();

    // ---- prologue: stage x tile (64KB) through buf region, hoist to regs ----
    #pragma unroll
    for (int i = 0; i < 8; i++) {
        int idx2 = (wid << 3) + i;
        int row = ((idx2 >> 4) << 5) + (lane & 31);
        gload16(xb + ((size_t)s_tok[row] << 8) + ((idx2 & 15) << 4) + (hi << 3),
                smem + (idx2 << 10));
    }
    asm volatile("s_waitcnt vmcnt(0)" ::: "memory");
    __syncthreads();

    bf16x8 xr[16];     // m-tile wr, 16 k-slices: 64 VGPR
    #pragma unroll
    for (int ks = 0; ks < 16; ks++)
        xr[ks] = *(const bf16x8*)(smem + (wr << 14) + (ks << 10) + (lane << 4));
    __syncthreads();

    // stage chunk 0 -> buf0
    STAGE_CHUNK(0, smem)
    asm volatile("s_waitcnt vmcnt(0)" ::: "memory");
    __syncthreads();   // one-time full drain

    f32x16 acc2[4];
    #pragma unroll
    for (int ct = 0; ct < 4; ct++) acc2[ct] = (f32x16)(0.0f);

    for (int ch = 0; ch < NCH; ch++) {
        int cur = ch & 1;
        const char* cbuf = smem + (cur << 16);

        // ---- stage next chunk at TOP (in flight across the whole chunk) ----
        if (ch + 1 < NCH) {
            char* nbuf = smem + ((cur ^ 1) << 16);
            STAGE_CHUNK(ch + 1, nbuf)
        }

        // ---- phase 1: Ht = W1ch x X^T, dual chains (slots: wc*16+ks) ----
        const char* w1b = cbuf + (wc << 14) + (lane << 4);
        f32x16 acc1a = (f32x16)(0.0f), acc1b = (f32x16)(0.0f);
        #pragma unroll
        for (int ks = 0; ks < 8; ks++) {
            bf16x8 a0 = *(const bf16x8*)(w1b + ((2 * ks) << 10));
            bf16x8 a1 = *(const bf16x8*)(w1b + ((2 * ks + 1) << 10));
            acc1a = __builtin_amdgcn_mfma_f32_32x32x16_bf16(a0, xr[2 * ks], acc1a, 0, 0, 0);
            acc1b = __builtin_amdgcn_mfma_f32_32x32x16_bf16(a1, xr[2 * ks + 1], acc1b, 0, 0, 0);
        }

        // bias + relu -> bf16 B-frags (chunk k-slices 2wc, 2wc+1)
        float h[16];
        #pragma unroll
        for (int r = 0; r < 16; r++) {
            int fl = (wc << 5) + (r & 3) + ((r >> 2) << 3) + (hi << 2);
            h[r] = fmaxf(acc1a[r] + acc1b[r] + b1s[(ch << 6) + fl], 0.f);
        }
        u32 w[8];
        #pragma unroll
        for (int t = 0; t < 8; t++)
            asm("v_cvt_pk_bf16_f32 %0, %1, %2" : "=v"(w[t]) : "v"(h[2 * t]), "v"(h[2 * t + 1]));
        asm volatile("v_permlane32_swap_b32 %0, %1" : "+v"(w[0]), "+v"(w[2]));
        asm volatile("v_permlane32_swap_b32 %0, %1" : "+v"(w[1]), "+v"(w[3]));
        asm volatile("v_permlane32_swap_b32 %0, %1" : "+v"(w[4]), "+v"(w[6]));
        asm volatile("v_permlane32_swap_b32 %0, %1" : "+v"(w[5]), "+v"(w[7]));
        union { u32x4 u; bf16x8 v; } fr0, fr1, pr0, pr1;
        fr0.u = (u32x4){w[0], w[1], w[2], w[3]};
        fr1.u = (u32x4){w[4], w[5], w[6], w[7]};

        // publish own Ht frags to hs[wr][2wc + 0/1]
        *(u32x4*)(smem + HS_OFF + (wr << 12) + ((wc << 1) << 10) + (lane << 4)) = fr0.u;
        *(u32x4*)(smem + HS_OFF + (wr << 12) + (((wc << 1) + 1) << 10) + (lane << 4)) = fr1.u;

        // mid barrier: lgkm only -- stage gloads stay in flight (vmcnt untouched)
        asm volatile("s_waitcnt lgkmcnt(0)" ::: "memory");
        __builtin_amdgcn_s_barrier();
        __builtin_amdgcn_sched_barrier(0);

        pr0.u = *(const u32x4*)(smem + HS_OFF + (wr << 12) + (((wc ^ 1) << 1) << 10) + (lane << 4));
        pr1.u = *(const u32x4*)(smem + HS_OFF + (wr << 12) + ((((wc ^ 1) << 1) + 1) << 10) + (lane << 4));

        // ---- phase 2: acc2[ctl] += W2frag(wc*4+ctl, s2) x Ht(s2), s2=0..3 ----
        const char* w2b = cbuf + 32768 + (wc << 14) + (lane << 4);
        bf16x8 bh0, bh1, bh2, bh3;
        if (wc == 0) { bh0 = fr0.v; bh1 = fr1.v; bh2 = pr0.v; bh3 = pr1.v; }
        else         { bh0 = pr0.v; bh1 = pr1.v; bh2 = fr0.v; bh3 = fr1.v; }

        #define P2_STEP(BH, S2)                                               \
            _Pragma("unroll")                                                 \
            for (int ctl = 0; ctl < 4; ctl++) {                               \
                bf16x8 a = *(const bf16x8*)(w2b + (ctl << 12) + ((S2) << 10));\
                acc2[ctl] = __builtin_amdgcn_mfma_f32_32x32x16_bf16(a, BH, acc2[ctl], 0, 0, 0); \
            }
        P2_STEP(bh0, 0)
        P2_STEP(bh1, 1)
        P2_STEP(bh2, 2)
        P2_STEP(bh3, 3)
        #undef P2_STEP

        // END barrier: explicit full drain -- stage is one full chunk old here
        asm volatile("s_waitcnt vmcnt(0) lgkmcnt(0)" ::: "memory");
        __builtin_amdgcn_s_barrier();
        __builtin_amdgcn_sched_barrier(0);
    }

    // ---- epilogue: wave owns (m-tile wr) x (c-half wc), FULL-K sums ----
    int m = (wr << 5) + (lane & 31);
    if (m < rows) {
        if (MODE == 0) {
            u16* yr = ybuf + ((size_t)(base + m) << 8) + (wc << 7);
            #pragma unroll
            for (int ctl = 0; ctl < 4; ctl++) {
                #pragma unroll
                for (int rq = 0; rq < 4; rq++) {
                    int c = (ctl << 5) + (rq << 3) + (hi << 2);
                    u16x4 o;
                    o[0] = f2bf(acc2[ctl][4 * rq]);
                    o[1] = f2bf(acc2[ctl][4 * rq + 1]);
                    o[2] = f2bf(acc2[ctl][4 * rq + 2]);
                    o[3] = f2bf(acc2[ctl][4 * rq + 3]);
                    *(u16x4*)(yr + c) = o;
                }
            }
        } else {
            float wgt_m = s_w[m];
            float* orow = out + ((size_t)s_tok[m] << 8) + (wc << 7);
            const float* b2w = b2e + (wc << 7);
            #pragma unroll
            for (int ctl = 0; ctl < 4; ctl++) {
                #pragma unroll
                for (int rq = 0; rq < 4; rq++) {
                    int c = (ctl << 5) + (rq << 3) + (hi << 2);
                    #pragma unroll
                    for (int l2 = 0; l2 < 4; l2++)
                        atomicAdd(&orow[c + l2],
                                  wgt_m * (acc2[ctl][4 * rq + l2] + b2w[c + l2]));
                }
            }
        }
    }
}

__global__ __launch_bounds__(256) void combine_kernel(
    const u16* __restrict__ ybuf, const int* __restrict__ tidx,
    const float* __restrict__ tw, const int* __restrict__ pairpos,
    const float* __restrict__ b2, float* __restrict__ out)
{
    int idx = blockIdx.x * 256 + threadIdx.x;
    int n = idx >> 6;
    int q = (idx & 63) << 2;
    int e0 = tidx[2 * n], e1 = tidx[2 * n + 1];
    float w0 = tw[2 * n], w1 = tw[2 * n + 1];
    int p0 = pairpos[2 * n], p1 = pairpos[2 * n + 1];
    u16x4 y0 = *(const u16x4*)(ybuf + ((size_t)p0 << 8) + q);
    u16x4 y1 = *(const u16x4*)(ybuf + ((size_t)p1 << 8) + q);
    float4 c0 = *(const float4*)(b2 + (e0 << 8) + q);
    float4 c1 = *(const float4*)(b2 + (e1 << 8) + q);
    float4 o;
    o.x = w0 * (bf2f(y0[0]) + c0.x) + w1 * (bf2f(y1[0]) + c1.x);
    o.y = w0 * (bf2f(y0[1]) + c0.y) + w1 * (bf2f(y1[1]) + c1.y);
    o.z = w0 * (bf2f(y0[2]) + c0.z) + w1 * (bf2f(y1[2]) + c1.z);
    o.w = w0 * (bf2f(y0[3]) + c0.w) + w1 * (bf2f(y1[3]) + c1.w);
    *(float4*)(out + ((size_t)n << 8) + q) = o;
}

extern "C" void kernel_launch(void* const* d_in, const int* in_sizes, int n_in,
                              void* d_out, int out_size, void* d_ws, size_t ws_size,
                              hipStream_t stream)
{
    const float* x   = (const float*)d_in[0];
    const float* gW  = (const float*)d_in[1];
    const float* gb  = (const float*)d_in[2];
    const float* W1  = (const float*)d_in[3];
    const float* b1  = (const float*)d_in[4];
    const float* W2  = (const float*)d_in[5];
    const float* b2  = (const float*)d_in[6];
    float* out = (float*)d_out;

    char* ws = (char*)d_ws;
    int*   topk_idx = (int*)(ws + 0);
    float* topk_w   = (float*)(ws + 262144);
    int*   tok      = (int*)(ws + 524288);
    float* wgt      = (float*)(ws + 786432);
    int*   pairpos  = (int*)(ws + 1048576);
    int*   counts   = (int*)(ws + 1310720);
    int*   fill     = (int*)(ws + 1310784);
    int*   offs     = (int*)(ws + 1310848);
    int*   tp       = (int*)(ws + 1310916);

    const size_t XB_OFF  = 2097152;
    const size_t W1F_OFF = 18874368;
    const size_t W2F_OFF = 27262976;
    const size_t Y_OFF   = 35651584;
    const size_t WS_FULL = Y_OFF + (size_t)2 * N_TOK * C_DIM * 2;  // bf16 ybuf

    u16* xb  = (u16*)(ws + XB_OFF);
    u16* w1f = (u16*)(ws + W1F_OFF);
    u16* w2f = (u16*)(ws + W2F_OFF);
    u16* ybuf = (u16*)(ws + Y_OFF);

    int mode = (ws_size >= WS_FULL) ? 0 : 1;

    float* ent_out = out + (size_t)N_TOK * C_DIM;

    if (mode == 0) {
        hipMemsetAsync(ent_out, 0, sizeof(float), stream);
    } else {
        hipMemsetAsync(d_out, 0, (size_t)(N_TOK * C_DIM + 1) * sizeof(float), stream);
    }
    hipMemsetAsync(counts, 0, 2 * E_NUM * sizeof(int), stream);

    gate_kernel<<<N_TOK / 64, 256, 0, stream>>>(x, gW, gb, ent_out,
                                                topk_idx, topk_w, counts, xb);
    prefix_kernel<<<1, 64, 0, stream>>>(counts, offs, tp);
    scatter_kernel<<<N_TOK / 256, 256, 0, stream>>>(topk_idx, topk_w, offs,
                                                    fill, tok, wgt, pairpos);
    tcvt_w1f<<<dim3(E_NUM, 32), 256, 0, stream>>>(W1, w1f);
    tcvt_w2f<<<dim3(E_NUM, 8, 4), 256, 0, stream>>>(W2, w2f);

    if (mode == 0) {
        ffn_mfma<0><<<NBLK, 512, 0, stream>>>(xb, w1f, w2f, b1, b2, tok, wgt,
                                              offs, tp, ybuf, out);
        combine_kernel<<<N_TOK * 64 / 256, 256, 0, stream>>>(ybuf, topk_idx,
                                                             topk_w, pairpos, b2, out);
    } else {
        ffn_mfma<1><<<NBLK, 512, 0, stream>>>(xb, w1f, w2f, b1, b2, tok, wgt,
                                              offs, tp, ybuf, out);
    }
}

// Round 12
// 181.520 us; speedup vs baseline: 1.2796x; 1.0106x over previous
//
#include <hip/hip_runtime.h>
#include <hip/hip_bf16.h>
#include <math.h>

#define N_TOK 32768
#define C_DIM 256
#define F_DIM 1024
#define E_NUM 16
#define TILE_R 128
#define NCH 32
#define NBLK 544   // 8 XCD groups x 68

typedef unsigned short u16;
typedef unsigned int u32;
typedef __attribute__((ext_vector_type(4))) u16 u16x4;
typedef __attribute__((ext_vector_type(8))) u16 u16x8;
typedef __attribute__((ext_vector_type(8))) short bf16x8;
typedef __attribute__((ext_vector_type(4))) u32 u32x4;
typedef __attribute__((ext_vector_type(16))) float f32x16;

#define AS1 __attribute__((address_space(1)))
#define AS3 __attribute__((address_space(3)))

// async global->LDS: LDS dest = wave-uniform base + lane*16; global src per-lane
__device__ __forceinline__ void gload16(const void* g, void* lds) {
    __builtin_amdgcn_global_load_lds((const AS1 u32*)(uintptr_t)g,
                                     (AS3 u32*)(u32)(uintptr_t)lds, 16, 0, 0);
}

__device__ __forceinline__ u16 f2bf(float f) {
    union { float f; u32 u; } v; v.f = f;
    u32 r = v.u + 0x7fffu + ((v.u >> 16) & 1u);   // RNE
    return (u16)(r >> 16);
}

__device__ __forceinline__ float bf2f(u16 b) {
    union { u32 u; float f; } v; v.u = ((u32)b) << 16;
    return v.f;
}

// ---------------- workspace layout (bytes) ----------------
// 0        topk_idx int[2N]
// 262144   topk_w   f32[2N]
// 524288   tok      int[2N]
// 786432   wgt      f32[2N]
// 1048576  pairpos  int[2N]
// 1310720  counts[16] fill[16] offs[17] tp[17]
// 2097152  xb   bf16[N][C]
// 18874368 w1f  frag-linear bf16 [(e*32+ft)*16+ks][64 lanes][8]
// 27262976 w2f  frag-linear bf16 [(e*8+ct)*64+kf][64 lanes][8]
// 35651584 ybuf bf16[2N][C]

// ---- gate: 64 tokens/block, 4 lanes/token, fused x->bf16 conversion ----
__global__ __launch_bounds__(256) void gate_kernel(
    const float* __restrict__ x, const float* __restrict__ gW,
    const float* __restrict__ gb, float* __restrict__ ent_out,
    int* __restrict__ tidx, float* __restrict__ tw, int* __restrict__ counts,
    u16* __restrict__ xb)
{
    __shared__ float gws[E_NUM * C_DIM];
    __shared__ float gbs[E_NUM];
    __shared__ float went[4];
    __shared__ int lc[E_NUM];
    int tid = threadIdx.x;

    for (int i = tid; i < E_NUM * C_DIM / 4; i += 256)
        ((float4*)gws)[i] = ((const float4*)gW)[i];
    if (tid < E_NUM) { gbs[tid] = gb[tid]; lc[tid] = 0; }
    __syncthreads();

    int tok = tid >> 2, q = tid & 3;
    int n = blockIdx.x * 64 + tok;
    const float* xr = x + (size_t)n * C_DIM;

    float4 xv[16];
    #pragma unroll
    for (int j = 0; j < 16; j++)
        xv[j] = *(const float4*)(xr + j * 16 + q * 4);

    #pragma unroll
    for (int j = 0; j < 16; j++) {
        u16x4 o;
        o[0] = f2bf(xv[j].x); o[1] = f2bf(xv[j].y);
        o[2] = f2bf(xv[j].z); o[3] = f2bf(xv[j].w);
        *(u16x4*)(xb + (size_t)n * C_DIM + j * 16 + q * 4) = o;
    }

    float lg[E_NUM];
    #pragma unroll
    for (int e = 0; e < E_NUM; e++) lg[e] = 0.f;
    #pragma unroll
    for (int j = 0; j < 16; j++) {
        #pragma unroll
        for (int e = 0; e < E_NUM; e++) {
            float4 g = *(const float4*)(gws + e * C_DIM + j * 16 + q * 4);
            lg[e] += xv[j].x * g.x + xv[j].y * g.y + xv[j].z * g.z + xv[j].w * g.w;
        }
    }
    #pragma unroll
    for (int e = 0; e < E_NUM; e++) {
        lg[e] += __shfl_xor(lg[e], 1);
        lg[e] += __shfl_xor(lg[e], 2);
        lg[e] += gbs[e];
    }

    float m = lg[0];
    #pragma unroll
    for (int e = 1; e < E_NUM; e++) m = fmaxf(m, lg[e]);
    float s = 0.f, ex[E_NUM];
    #pragma unroll
    for (int e = 0; e < E_NUM; e++) { ex[e] = __expf(lg[e] - m); s += ex[e]; }
    float inv = 1.f / s;
    float ent = 0.f;
    #pragma unroll
    for (int e = 0; e < E_NUM; e++) {
        float p = ex[e] * inv;
        ent -= p * logf(p + 1e-8f);
    }

    float v0 = -1e30f, v1 = -1e30f;
    int i0 = 0, i1 = 0;
    #pragma unroll
    for (int e = 0; e < E_NUM; e++) {
        float l = lg[e];
        if (l > v0) { v1 = v0; i1 = i0; v0 = l; i0 = e; }
        else if (l > v1) { v1 = l; i1 = e; }
    }
    if (q == 0) {
        float w1e = __expf(v1 - v0);
        float z = 1.f + w1e;
        tidx[2 * n] = i0; tidx[2 * n + 1] = i1;
        tw[2 * n] = 1.f / z; tw[2 * n + 1] = w1e / z;
        atomicAdd(&lc[i0], 1);
        atomicAdd(&lc[i1], 1);
    }

    float v = ent;   // 4x duplicated per token -> scale 1/(4N)
    for (int off = 32; off > 0; off >>= 1) v += __shfl_down(v, off);
    int wid = tid >> 6, lane = tid & 63;
    if (lane == 0) went[wid] = v;
    __syncthreads();
    if (tid == 0)
        atomicAdd(ent_out, (went[0] + went[1] + went[2] + went[3]) * (1.0f / (4.0f * N_TOK)));
    if (tid < E_NUM && lc[tid]) atomicAdd(&counts[tid], lc[tid]);
}

__global__ void prefix_kernel(const int* __restrict__ counts,
                              int* __restrict__ offs, int* __restrict__ tp)
{
    if (threadIdx.x == 0 && blockIdx.x == 0) {
        int o = 0, t = 0;
        offs[0] = 0; tp[0] = 0;
        for (int e = 0; e < E_NUM; e++) {
            o += counts[e];
            t += (counts[e] + TILE_R - 1) / TILE_R;
            offs[e + 1] = o;
            tp[e + 1] = t;
        }
    }
}

__global__ __launch_bounds__(256) void scatter_kernel(
    const int* __restrict__ tidx, const float* __restrict__ tw,
    const int* __restrict__ offs, int* __restrict__ fill,
    int* __restrict__ tok, float* __restrict__ wgt, int* __restrict__ pairpos)
{
    __shared__ int lc[E_NUM], lbase[E_NUM];
    int tid = threadIdx.x;
    if (tid < E_NUM) lc[tid] = 0;
    __syncthreads();
    int n = blockIdx.x * 256 + tid;
    int e0 = tidx[2 * n], e1 = tidx[2 * n + 1];
    int r0 = atomicAdd(&lc[e0], 1);
    int r1 = atomicAdd(&lc[e1], 1);
    __syncthreads();
    if (tid < E_NUM) lbase[tid] = offs[tid] + atomicAdd(&fill[tid], lc[tid]);
    __syncthreads();
    int p0 = lbase[e0] + r0, p1 = lbase[e1] + r1;
    tok[p0] = n; wgt[p0] = tw[2 * n];     pairpos[2 * n] = p0;
    tok[p1] = n; wgt[p1] = tw[2 * n + 1]; pairpos[2 * n + 1] = p1;
}

// ---- frag-izers: emit frag-linear bf16 layouts (1 KB contiguous per frag) ----
// w1f frag (e,ft,ks): lane l, elem j = W1[e][c = ks*16+(l>>5)*8+j][f = ft*32+(l&31)]
__global__ __launch_bounds__(256) void tcvt_w1f(
    const float* __restrict__ W1, u16* __restrict__ w1f)
{
    __shared__ float t[256][33];
    int e = blockIdx.x, ft = blockIdx.y;
    int tid = threadIdx.x;
    const float* src = W1 + ((size_t)e * C_DIM) * F_DIM + (size_t)tid * F_DIM + ft * 32;
    #pragma unroll
    for (int j = 0; j < 8; j++) {
        float4 v = *(const float4*)(src + j * 4);
        t[tid][j * 4] = v.x; t[tid][j * 4 + 1] = v.y;
        t[tid][j * 4 + 2] = v.z; t[tid][j * 4 + 3] = v.w;
    }
    __syncthreads();
    int l = tid & 63, ksq = tid >> 6;
    #pragma unroll
    for (int p = 0; p < 4; p++) {
        int ks = ksq * 4 + p;
        int c0 = ks * 16 + (l >> 5) * 8;
        u16x8 o;
        #pragma unroll
        for (int j = 0; j < 8; j++) o[j] = f2bf(t[c0 + j][l & 31]);
        *(u16x8*)(w1f + ((size_t)((e * 32 + ft) * 16 + ks)) * 512 + l * 8) = o;
    }
}

// w2f frag (e,ct,kf): lane l, elem j = W2[e][f = kf*16+(l>>5)*8+j][c = ct*32+(l&31)]
__global__ __launch_bounds__(256) void tcvt_w2f(
    const float* __restrict__ W2, u16* __restrict__ w2f)
{
    __shared__ float t[256][33];
    int e = blockIdx.x, ct = blockIdx.y, fq = blockIdx.z;
    int tid = threadIdx.x;
    const float* src = W2 + ((size_t)e * F_DIM + fq * 256 + tid) * C_DIM + ct * 32;
    #pragma unroll
    for (int j = 0; j < 8; j++) {
        float4 v = *(const float4*)(src + j * 4);
        t[tid][j * 4] = v.x; t[tid][j * 4 + 1] = v.y;
        t[tid][j * 4 + 2] = v.z; t[tid][j * 4 + 3] = v.w;
    }
    __syncthreads();
    int l = tid & 63, kq = tid >> 6;
    #pragma unroll
    for (int p = 0; p < 4; p++) {
        int kfl = kq * 4 + p;
        int f0 = kfl * 16 + (l >> 5) * 8;
        u16x8 o;
        #pragma unroll
        for (int j = 0; j < 8; j++) o[j] = f2bf(t[f0 + j][l & 31]);
        *(u16x8*)(w2f + ((size_t)((e * 8 + ct) * 64 + fq * 16 + kfl)) * 512 + l * 8) = o;
    }
}

// ---- FFN: 128-token tile, 4 waves (2 blocks/CU), 32x32x16 MFMA ----
// LDS 70656: buf0 @0 (w1 16K | w2 16K), buf1 @32768, b1s @65536 (4K),
// s_tok @69632, s_w @70144. FCH=32, NCH=32.
// Wave = m-tile (4 x 32 rows). p1: full-K Ht for own m-tile (16 MFMA,
// lane-local -> NO exchange, NO mid barrier). p2: all 8 c-tiles (16 MFMA,
// acc2 = 8 x f32x16). ONE barrier per chunk; stage-at-top, drained at end
// (aged one full chunk). Zero redundant MFMAs.
#define B1S_OFF 65536

// stage chunk CHN (32 f): 4 w1 frags + 4 w2 frags per wave
#define STAGE_CHUNK(CHN, NBUF)                                                \
    {                                                                         \
        _Pragma("unroll")                                                     \
        for (int i = 0; i < 4; i++) {                                         \
            int ks = (wid << 2) + i;                                          \
            gload16(w1fe + (((size_t)((CHN) << 4) + ks) << 9) + (lane << 3),  \
                    (NBUF) + (ks << 10));                                     \
        }                                                                     \
        _Pragma("unroll")                                                     \
        for (int i = 0; i < 4; i++) {                                         \
            int g = (wid << 2) + i;                                           \
            int ct = g >> 1, s2 = g & 1;                                      \
            gload16(w2fe + (((size_t)(ct << 6) + ((CHN) << 1) + s2) << 9) + (lane << 3), \
                    (NBUF) + 16384 + (g << 10));                              \
        }                                                                     \
    }

template <int MODE>
__global__ __launch_bounds__(256, 2) void ffn_mfma(
    const u16* __restrict__ xb, const u16* __restrict__ w1f,
    const u16* __restrict__ w2f, const float* __restrict__ b1,
    const float* __restrict__ b2, const int* __restrict__ tok,
    const float* __restrict__ wgt, const int* __restrict__ offs,
    const int* __restrict__ tp, u16* __restrict__ ybuf,
    float* __restrict__ out)
{
    __shared__ __align__(1024) char smem[70656];
    int* s_tok = (int*)(smem + 69632);
    float* s_w = (float*)(smem + 70144);
    float* b1s = (float*)(smem + B1S_OFF);

    int bidx = blockIdx.x;
    int b = (bidx & 7) * (NBLK / 8) + (bidx >> 3);   // XCD expert-locality remap
    if (b >= tp[E_NUM]) return;
    int e = 0;
    while (b >= tp[e + 1]) e++;
    int base = offs[e] + ((b - tp[e]) << 7);
    int rows = offs[e + 1] - base; if (rows > TILE_R) rows = TILE_R;

    int tid = threadIdx.x;
    int lane = tid & 63, wid = tid >> 6;
    int hi = lane >> 5;

    const u16* w1fe = w1f + ((size_t)e << 9) * 512;   // e * 512 frags * 512 u16
    const u16* w2fe = w2f + ((size_t)e << 9) * 512;
    const float* b1e = b1 + e * F_DIM;
    const float* b2e = b2 + e * C_DIM;

    if (tid < TILE_R) {
        int src = (tid < rows) ? base + tid : base;
        s_tok[tid] = tok[src];
        s_w[tid] = (tid < rows) ? wgt[src] : 0.f;
    }
    ((float4*)b1s)[tid] = ((const float4*)b1e)[tid];   // 256 x 16B = 4KB
    __syncthreads();

    // ---- prologue: stage x tile (64KB) through buf region, hoist to regs ----
    #pragma unroll
    for (int i = 0; i < 16; i++) {
        int idx2 = (wid << 4) + i;                 // [mtile 4][ks 16]
        int row = ((idx2 >> 4) << 5) + (lane & 31);
        gload16(xb + ((size_t)s_tok[row] << 8) + ((idx2 & 15) << 4) + (hi << 3),
                smem + (idx2 << 10));
    }
    asm volatile("s_waitcnt vmcnt(0)" ::: "memory");
    __syncthreads();

    bf16x8 xr[16];     // m-tile wid, 16 k-slices: 64 VGPR
    #pragma unroll
    for (int ks = 0; ks < 16; ks++)
        xr[ks] = *(const bf16x8*)(smem + (wid << 14) + (ks << 10) + (lane << 4));
    __syncthreads();

    // stage chunk 0 -> buf0
    STAGE_CHUNK(0, smem)
    asm volatile("s_waitcnt vmcnt(0)" ::: "memory");
    __syncthreads();   // one-time full drain

    f32x16 acc2[8];
    #pragma unroll
    for (int ct = 0; ct < 8; ct++) acc2[ct] = (f32x16)(0.0f);

    for (int ch = 0; ch < NCH; ch++) {
        int cur = ch & 1;
        const char* cbuf = smem + (cur << 15);

        // stage next chunk at TOP (in flight across the whole chunk body)
        if (ch + 1 < NCH) {
            char* nbuf = smem + ((cur ^ 1) << 15);
            STAGE_CHUNK(ch + 1, nbuf)
        }

        // ---- phase 1: Ht(32f x own 32m) = W1ch x X^T, dual chains ----
        const char* w1b = cbuf + (lane << 4);
        f32x16 acc1a = (f32x16)(0.0f), acc1b = (f32x16)(0.0f);
        #pragma unroll
        for (int ks = 0; ks < 8; ks++) {
            bf16x8 a0 = *(const bf16x8*)(w1b + ((2 * ks) << 10));
            bf16x8 a1 = *(const bf16x8*)(w1b + ((2 * ks + 1) << 10));
            acc1a = __builtin_amdgcn_mfma_f32_32x32x16_bf16(a0, xr[2 * ks], acc1a, 0, 0, 0);
            acc1b = __builtin_amdgcn_mfma_f32_32x32x16_bf16(a1, xr[2 * ks + 1], acc1b, 0, 0, 0);
        }

        // bias + relu -> bf16 B-frags (chunk k-slices 0,1), fully in-register
        float h[16];
        #pragma unroll
        for (int r = 0; r < 16; r++) {
            int fl = (r & 3) + ((r >> 2) << 3) + (hi << 2);
            h[r] = fmaxf(acc1a[r] + acc1b[r] + b1s[(ch << 5) + fl], 0.f);
        }
        u32 w[8];
        #pragma unroll
        for (int t = 0; t < 8; t++)
            asm("v_cvt_pk_bf16_f32 %0, %1, %2" : "=v"(w[t]) : "v"(h[2 * t]), "v"(h[2 * t + 1]));
        asm volatile("v_permlane32_swap_b32 %0, %1" : "+v"(w[0]), "+v"(w[2]));
        asm volatile("v_permlane32_swap_b32 %0, %1" : "+v"(w[1]), "+v"(w[3]));
        asm volatile("v_permlane32_swap_b32 %0, %1" : "+v"(w[4]), "+v"(w[6]));
        asm volatile("v_permlane32_swap_b32 %0, %1" : "+v"(w[5]), "+v"(w[7]));
        union { u32x4 u; bf16x8 v; } fr0, fr1;
        fr0.u = (u32x4){w[0], w[1], w[2], w[3]};
        fr1.u = (u32x4){w[4], w[5], w[6], w[7]};

        // ---- phase 2: acc2[ctl] += W2frag(ctl, s2) x Ht(s2), s2 = 0,1 ----
        const char* w2b = cbuf + 16384 + (lane << 4);
        #pragma unroll
        for (int ctl = 0; ctl < 8; ctl++) {
            bf16x8 a0 = *(const bf16x8*)(w2b + ((ctl << 1) << 10));
            bf16x8 a1 = *(const bf16x8*)(w2b + (((ctl << 1) + 1) << 10));
            acc2[ctl] = __builtin_amdgcn_mfma_f32_32x32x16_bf16(a0, fr0.v, acc2[ctl], 0, 0, 0);
            acc2[ctl] = __builtin_amdgcn_mfma_f32_32x32x16_bf16(a1, fr1.v, acc2[ctl], 0, 0, 0);
        }

        // END barrier: full drain -- stage is one full chunk body old here
        asm volatile("s_waitcnt vmcnt(0) lgkmcnt(0)" ::: "memory");
        __builtin_amdgcn_s_barrier();
        __builtin_amdgcn_sched_barrier(0);
    }

    // ---- epilogue: wave owns m-tile wid, ALL 256 c, full-K sums ----
    int m = (wid << 5) + (lane & 31);
    if (m < rows) {
        if (MODE == 0) {
            u16* yr = ybuf + ((size_t)(base + m) << 8);
            #pragma unroll
            for (int ctl = 0; ctl < 8; ctl++) {
                #pragma unroll
                for (int rq = 0; rq < 4; rq++) {
                    int c = (ctl << 5) + (rq << 3) + (hi << 2);
                    u16x4 o;
                    o[0] = f2bf(acc2[ctl][4 * rq]);
                    o[1] = f2bf(acc2[ctl][4 * rq + 1]);
                    o[2] = f2bf(acc2[ctl][4 * rq + 2]);
                    o[3] = f2bf(acc2[ctl][4 * rq + 3]);
                    *(u16x4*)(yr + c) = o;
                }
            }
        } else {
            float wgt_m = s_w[m];
            float* orow = out + ((size_t)s_tok[m] << 8);
            #pragma unroll
            for (int ctl = 0; ctl < 8; ctl++) {
                #pragma unroll
                for (int rq = 0; rq < 4; rq++) {
                    int c = (ctl << 5) + (rq << 3) + (hi << 2);
                    #pragma unroll
                    for (int l2 = 0; l2 < 4; l2++)
                        atomicAdd(&orow[c + l2],
                                  wgt_m * (acc2[ctl][4 * rq + l2] + b2e[c + l2]));
                }
            }
        }
    }
}

__global__ __launch_bounds__(256) void combine_kernel(
    const u16* __restrict__ ybuf, const int* __restrict__ tidx,
    const float* __restrict__ tw, const int* __restrict__ pairpos,
    const float* __restrict__ b2, float* __restrict__ out)
{
    int idx = blockIdx.x * 256 + threadIdx.x;
    int n = idx >> 6;
    int q = (idx & 63) << 2;
    int e0 = tidx[2 * n], e1 = tidx[2 * n + 1];
    float w0 = tw[2 * n], w1 = tw[2 * n + 1];
    int p0 = pairpos[2 * n], p1 = pairpos[2 * n + 1];
    u16x4 y0 = *(const u16x4*)(ybuf + ((size_t)p0 << 8) + q);
    u16x4 y1 = *(const u16x4*)(ybuf + ((size_t)p1 << 8) + q);
    float4 c0 = *(const float4*)(b2 + (e0 << 8) + q);
    float4 c1 = *(const float4*)(b2 + (e1 << 8) + q);
    float4 o;
    o.x = w0 * (bf2f(y0[0]) + c0.x) + w1 * (bf2f(y1[0]) + c1.x);
    o.y = w0 * (bf2f(y0[1]) + c0.y) + w1 * (bf2f(y1[1]) + c1.y);
    o.z = w0 * (bf2f(y0[2]) + c0.z) + w1 * (bf2f(y1[2]) + c1.z);
    o.w = w0 * (bf2f(y0[3]) + c0.w) + w1 * (bf2f(y1[3]) + c1.w);
    *(float4*)(out + ((size_t)n << 8) + q) = o;
}

extern "C" void kernel_launch(void* const* d_in, const int* in_sizes, int n_in,
                              void* d_out, int out_size, void* d_ws, size_t ws_size,
                              hipStream_t stream)
{
    const float* x   = (const float*)d_in[0];
    const float* gW  = (const float*)d_in[1];
    const float* gb  = (const float*)d_in[2];
    const float* W1  = (const float*)d_in[3];
    const float* b1  = (const float*)d_in[4];
    const float* W2  = (const float*)d_in[5];
    const float* b2  = (const float*)d_in[6];
    float* out = (float*)d_out;

    char* ws = (char*)d_ws;
    int*   topk_idx = (int*)(ws + 0);
    float* topk_w   = (float*)(ws + 262144);
    int*   tok      = (int*)(ws + 524288);
    float* wgt      = (float*)(ws + 786432);
    int*   pairpos  = (int*)(ws + 1048576);
    int*   counts   = (int*)(ws + 1310720);
    int*   fill     = (int*)(ws + 1310784);
    int*   offs     = (int*)(ws + 1310848);
    int*   tp       = (int*)(ws + 1310916);

    const size_t XB_OFF  = 2097152;
    const size_t W1F_OFF = 18874368;
    const size_t W2F_OFF = 27262976;
    const size_t Y_OFF   = 35651584;
    const size_t WS_FULL = Y_OFF + (size_t)2 * N_TOK * C_DIM * 2;  // bf16 ybuf

    u16* xb  = (u16*)(ws + XB_OFF);
    u16* w1f = (u16*)(ws + W1F_OFF);
    u16* w2f = (u16*)(ws + W2F_OFF);
    u16* ybuf = (u16*)(ws + Y_OFF);

    int mode = (ws_size >= WS_FULL) ? 0 : 1;

    float* ent_out = out + (size_t)N_TOK * C_DIM;

    if (mode == 0) {
        hipMemsetAsync(ent_out, 0, sizeof(float), stream);
    } else {
        hipMemsetAsync(d_out, 0, (size_t)(N_TOK * C_DIM + 1) * sizeof(float), stream);
    }
    hipMemsetAsync(counts, 0, 2 * E_NUM * sizeof(int), stream);

    gate_kernel<<<N_TOK / 64, 256, 0, stream>>>(x, gW, gb, ent_out,
                                                topk_idx, topk_w, counts, xb);
    prefix_kernel<<<1, 64, 0, stream>>>(counts, offs, tp);
    scatter_kernel<<<N_TOK / 256, 256, 0, stream>>>(topk_idx, topk_w, offs,
                                                    fill, tok, wgt, pairpos);
    tcvt_w1f<<<dim3(E_NUM, 32), 256, 0, stream>>>(W1, w1f);
    tcvt_w2f<<<dim3(E_NUM, 8, 4), 256, 0, stream>>>(W2, w2f);

    if (mode == 0) {
        ffn_mfma<0><<<NBLK, 256, 0, stream>>>(xb, w1f, w2f, b1, b2, tok, wgt,
                                              offs, tp, ybuf, out);
        combine_kernel<<<N_TOK * 64 / 256, 256, 0, stream>>>(ybuf, topk_idx,
                                                             topk_w, pairpos, b2, out);
    } else {
        ffn_mfma<1><<<NBLK, 256, 0, stream>>>(xb, w1f, w2f, b1, b2, tok, wgt,
                                              offs, tp, ybuf, out);
    }
}